// Round 7
// baseline (293.921 us; speedup 1.0000x reference)
//
#include <hip/hip_runtime.h>
#include <hip/hip_cooperative_groups.h>
#include <math.h>

namespace cg = cooperative_groups;

#define BB 64
#define MM 128
#define DDIM 2048
#define KK 32
#define NFR (BB*MM)              // 8192
#define OUTROW (DDIM + KK*DDIM)  // 67584

typedef __attribute__((ext_vector_type(8))) short bf16x8;
typedef __attribute__((ext_vector_type(4))) float f32x4;

// float -> bf16 RNE (inputs finite; no NaN handling needed)
__device__ __forceinline__ short f2bf(float f) {
  unsigned u = __builtin_bit_cast(unsigned, f);
  u += 0x7fffu + ((u >> 16) & 1u);
  return (short)(u >> 16);
}
__device__ __forceinline__ unsigned pack2(float lo, float hi) {
  return (unsigned)(unsigned short)f2bf(lo) | ((unsigned)(unsigned short)f2bf(hi) << 16);
}

// ---------------------------------------------------------------------------
// Single cooperative kernel, 512 blocks x 256 threads, 4 phases:
//  P0: W fp32->bf16 (blocks 0..31)
//  P1: logits GEMM (bf16 MFMA) + ssq + softmax -> a'T bf16, asum partials
//  P2: vlad GEMM (bf16 MFMA, swizzled LDS x-transpose) + avgpool + raw vlad
//  P3: intra+global L2 norm, in-place scale
// grid.sync() between phases (all 512 blocks co-resident at 2 blocks/CU).
// ---------------------------------------------------------------------------
__global__ __launch_bounds__(256, 2) void k_fused(
    const float* __restrict__ x, const int* __restrict__ lengths,
    const float* __restrict__ W, const float* __restrict__ Cc,
    float* __restrict__ out, short* __restrict__ Wb,
    short* __restrict__ aT, float* __restrict__ asum_p,
    float* __restrict__ ssqp) {
  cg::grid_group grid = cg::this_grid();
  const int t = threadIdx.x, wv = t >> 6, lane = t & 63;
  const int l15 = lane & 15, quad = lane >> 4;
  const int blk = blockIdx.x;

  __shared__ float sq[4][16];
  __shared__ float lg[4][16][33];
  __shared__ short xbt[4][64][40];   // [wave][d-local][swizzled m], rows 80B
  __shared__ float asl[KK];
  __shared__ float ssw[4][33];
  __shared__ float ssk[KK];

  // ================= P0: W -> bf16 =================
  if (blk < 32) {
    int i = (blk * 256 + t) * 8;
    float4 a = *(const float4*)(W + i);
    float4 b = *(const float4*)(W + i + 4);
    bf16x8 o = {f2bf(a.x), f2bf(a.y), f2bf(a.z), f2bf(a.w),
                f2bf(b.x), f2bf(b.y), f2bf(b.z), f2bf(b.w)};
    *(bf16x8*)(Wb + i) = o;
  }
  grid.sync();

  // ================= P1: logits + softmax =================
  {
    const int fg = blk;                // 0..511
    const int g0 = fg * 16;
    const int b  = fg >> 3;
    const int m0 = (fg & 7) * 16;
    const int len = lengths[b];

    const float* xrow = x + (size_t)(g0 + l15) * DDIM + wv * 512 + quad * 8;
    const short* w0   = Wb + l15 * DDIM + wv * 512 + quad * 8;
    const short* w1   = w0 + 16 * DDIM;

    f32x4 c0 = {0.f, 0.f, 0.f, 0.f}, c1 = {0.f, 0.f, 0.f, 0.f};
    float ssq = 0.f;
    #pragma unroll
    for (int s = 0; s < 16; ++s) {
      float4 xa = *(const float4*)(xrow + s * 32);
      float4 xc = *(const float4*)(xrow + s * 32 + 4);
      ssq = fmaf(xa.x, xa.x, ssq); ssq = fmaf(xa.y, xa.y, ssq);
      ssq = fmaf(xa.z, xa.z, ssq); ssq = fmaf(xa.w, xa.w, ssq);
      ssq = fmaf(xc.x, xc.x, ssq); ssq = fmaf(xc.y, xc.y, ssq);
      ssq = fmaf(xc.z, xc.z, ssq); ssq = fmaf(xc.w, xc.w, ssq);
      bf16x8 A = {f2bf(xa.x), f2bf(xa.y), f2bf(xa.z), f2bf(xa.w),
                  f2bf(xc.x), f2bf(xc.y), f2bf(xc.z), f2bf(xc.w)};
      bf16x8 B0 = *(const bf16x8*)(w0 + s * 32);
      bf16x8 B1 = *(const bf16x8*)(w1 + s * 32);
      c0 = __builtin_amdgcn_mfma_f32_16x16x32_bf16(A, B0, c0, 0, 0, 0);
      c1 = __builtin_amdgcn_mfma_f32_16x16x32_bf16(A, B1, c1, 0, 0, 0);
    }

    ssq += __shfl_xor(ssq, 16, 64);
    ssq += __shfl_xor(ssq, 32, 64);
    if (quad == 0) sq[wv][l15] = ssq;
    #pragma unroll
    for (int r = 0; r < 4; ++r) {
      lg[wv][quad * 4 + r][l15]      = c0[r];
      lg[wv][quad * 4 + r][16 + l15] = c1[r];
    }
    __syncthreads();

    const int fr = t >> 4, kk = (t & 15) * 2;
    float s0 = 0.f, s1 = 0.f;
    #pragma unroll
    for (int w = 0; w < 4; ++w) { s0 += lg[w][fr][kk]; s1 += lg[w][fr][kk + 1]; }
    float ss  = sq[0][fr] + sq[1][fr] + sq[2][fr] + sq[3][fr];
    float inv = 1.f / fmaxf(sqrtf(ss), 1e-12f);
    s0 *= inv; s1 *= inv;
    float mx = fmaxf(s0, s1);
    mx = fmaxf(mx, __shfl_xor(mx, 1, 64));
    mx = fmaxf(mx, __shfl_xor(mx, 2, 64));
    mx = fmaxf(mx, __shfl_xor(mx, 4, 64));
    mx = fmaxf(mx, __shfl_xor(mx, 8, 64));
    float e0 = __expf(s0 - mx), e1 = __expf(s1 - mx);
    float se = e0 + e1;
    se += __shfl_xor(se, 1, 64);
    se += __shfl_xor(se, 2, 64);
    se += __shfl_xor(se, 4, 64);
    se += __shfl_xor(se, 8, 64);
    const bool valid = (m0 + fr) < len;
    float rr = valid ? (1.f / se) : 0.f;
    float a0 = e0 * rr, a1 = e1 * rr;

    __syncthreads();
    lg[0][fr][kk] = a0; lg[0][fr][kk + 1] = a1;
    __syncthreads();
    if (t < KK) {
      float s = 0.f;
      #pragma unroll
      for (int f = 0; f < 16; ++f) s += lg[0][f][t];
      asum_p[(size_t)fg * KK + t] = s;
    }
    short* ap = aT + (size_t)b * KK * MM + m0 + fr;
    ap[(size_t)kk * MM]       = f2bf(a0 * inv);
    ap[(size_t)(kk + 1) * MM] = f2bf(a1 * inv);
  }
  grid.sync();

  // ================= P2: vlad GEMM =================
  {
    const int dc = blk & 7, b = blk >> 3;
    const int dw0 = dc * 256 + wv * 64;
    const int len = lengths[b];

    if (t < KK) {
      float s = 0.f;
      #pragma unroll
      for (int p = 0; p < 8; ++p) s += asum_p[(size_t)(b * 8 + p) * KK + t];
      asl[t] = s;
    }

    const float* xb  = x  + (size_t)b * MM * DDIM;
    const short* at0 = aT + (size_t)b * KK * MM + l15 * MM + quad * 8;

    f32x4 acc[2][4];
    #pragma unroll
    for (int kt = 0; kt < 2; ++kt)
      #pragma unroll
      for (int nt = 0; nt < 4; ++nt) acc[kt][nt] = (f32x4){0.f, 0.f, 0.f, 0.f};
    float avg[4] = {0.f, 0.f, 0.f, 0.f};

    const int q4   = l15 * 4;           // lane's 4 staged d-rows
    const int mrow = quad * 2;          // even m within pass group
    const int keyw = l15 & 3;           // store swizzle key = (row>>2)&3
    const int keyr = (l15 >> 2) & 3;    // read  swizzle key for row nt*16+l15

    for (int ms = 0; ms < 4; ++ms) {
      const int m0 = ms * 32;
      #pragma unroll
      for (int p = 0; p < 4; ++p) {
        int ml = p * 8 + mrow;          // logical m-local, even
        int m  = m0 + ml;
        const float* xr = xb + (size_t)m * DDIM + dw0 + q4;
        float4 v0 = *(const float4*)xr;
        float4 v1 = *(const float4*)(xr + DDIM);
        float f0 = (m < len) ? 1.f : 0.f;
        float f1 = (m + 1 < len) ? 1.f : 0.f;
        avg[0] = fmaf(v0.x, f0, fmaf(v1.x, f1, avg[0]));
        avg[1] = fmaf(v0.y, f0, fmaf(v1.y, f1, avg[1]));
        avg[2] = fmaf(v0.z, f0, fmaf(v1.z, f1, avg[2]));
        avg[3] = fmaf(v0.w, f0, fmaf(v1.w, f1, avg[3]));
        int mls = (p ^ keyw) * 8 + mrow;  // swizzled m-slot
        *(unsigned*)&xbt[wv][q4 + 0][mls] = pack2(v0.x, v1.x);
        *(unsigned*)&xbt[wv][q4 + 1][mls] = pack2(v0.y, v1.y);
        *(unsigned*)&xbt[wv][q4 + 2][mls] = pack2(v0.z, v1.z);
        *(unsigned*)&xbt[wv][q4 + 3][mls] = pack2(v0.w, v1.w);
      }
      // wave-private tile: same-wave DS ordering is program order
      bf16x8 A0 = *(const bf16x8*)(at0 + m0);
      bf16x8 A1 = *(const bf16x8*)(at0 + 16 * MM + m0);
      #pragma unroll
      for (int nt = 0; nt < 4; ++nt) {
        bf16x8 B = *(const bf16x8*)&xbt[wv][nt * 16 + l15][(quad ^ keyr) * 8];
        acc[0][nt] = __builtin_amdgcn_mfma_f32_16x16x32_bf16(A0, B, acc[0][nt], 0, 0, 0);
        acc[1][nt] = __builtin_amdgcn_mfma_f32_16x16x32_bf16(A1, B, acc[1][nt], 0, 0, 0);
      }
    }

    #pragma unroll
    for (int c = 0; c < 4; ++c) {
      avg[c] += __shfl_xor(avg[c], 16, 64);
      avg[c] += __shfl_xor(avg[c], 32, 64);
    }
    if (quad == 0) {
      float rl = 1.f / (float)len;
      *(float4*)(out + (size_t)b * OUTROW + dw0 + q4) =
          make_float4(avg[0] * rl, avg[1] * rl, avg[2] * rl, avg[3] * rl);
    }

    __syncthreads();   // asl ready
    float* orow = out + (size_t)b * OUTROW + DDIM;
    #pragma unroll
    for (int kt = 0; kt < 2; ++kt) {
      #pragma unroll
      for (int r = 0; r < 4; ++r) {
        const int k = kt * 16 + quad * 4 + r;
        const float as = asl[k];
        float sqv = 0.f;
        #pragma unroll
        for (int nt = 0; nt < 4; ++nt) {
          const int d = dw0 + nt * 16 + l15;
          float v = acc[kt][nt][r] - as * Cc[(size_t)k * DDIM + d];
          orow[(size_t)k * DDIM + d] = v;
          sqv = fmaf(v, v, sqv);
        }
        sqv += __shfl_xor(sqv, 1, 64);
        sqv += __shfl_xor(sqv, 2, 64);
        sqv += __shfl_xor(sqv, 4, 64);
        sqv += __shfl_xor(sqv, 8, 64);
        if (l15 == 0) ssw[wv][k] = sqv;
      }
    }
    __syncthreads();
    if (t < KK)
      ssqp[((size_t)dc * BB + b) * KK + t] =
          ssw[0][t] + ssw[1][t] + ssw[2][t] + ssw[3][t];
  }
  grid.sync();

  // ================= P3: normalize =================
  {
    const int dc = blk & 7, b = blk >> 3;
    if (t < KK) {
      float sk = 0.f;
      #pragma unroll
      for (int p = 0; p < 8; ++p)
        sk += ssqp[((size_t)p * BB + b) * KK + t];
      ssk[t] = sk;
    }
    __syncthreads();
    float gss = 0.f;
    #pragma unroll
    for (int k = 0; k < KK; ++k) {
      float nk = sqrtf(ssk[k]);
      float nn = nk * (1.f / fmaxf(nk, 1e-12f));
      gss += nn * nn;
    }
    float ginv = 1.f / fmaxf(sqrtf(gss), 1e-12f);
    float* orow = out + (size_t)b * OUTROW + DDIM + dc * 256 + t;
    #pragma unroll
    for (int k = 0; k < KK; ++k) {
      float iv = 1.f / fmaxf(sqrtf(ssk[k]), 1e-12f);
      float v = orow[(size_t)k * DDIM];
      orow[(size_t)k * DDIM] = v * (iv * ginv);
    }
  }
}

// ---------------------------------------------------------------------------
extern "C" void kernel_launch(void* const* d_in, const int* in_sizes, int n_in,
                              void* d_out, int out_size, void* d_ws, size_t ws_size,
                              hipStream_t stream) {
  const float* x       = (const float*)d_in[0];
  const int*   lengths = (const int*)d_in[1];
  const float* W       = (const float*)d_in[2];
  const float* C       = (const float*)d_in[3];
  float* out = (float*)d_out;

  short* Wb     = (short*)d_ws;                          // 32*2048 shorts
  short* aT     = Wb + (size_t)KK * DDIM;                // 64*32*128 shorts
  float* asum_p = (float*)(aT + (size_t)BB * KK * MM);   // 512*32
  float* ssqp   = asum_p + (size_t)512 * KK;             // 8*64*32

  void* args[] = {(void*)&x, (void*)&lengths, (void*)&W, (void*)&C,
                  (void*)&out, (void*)&Wb, (void*)&aT, (void*)&asum_p,
                  (void*)&ssqp};
  hipLaunchCooperativeKernel((const void*)k_fused, dim3(512), dim3(256),
                             args, 0, stream);
}

// Round 8
// 145.941 us; speedup vs baseline: 2.0140x; 2.0140x over previous
//
#include <hip/hip_runtime.h>
#include <math.h>

#define BB 64
#define MM 128
#define DDIM 2048
#define KK 32
#define NFR (BB*MM)              // 8192
#define OUTROW (DDIM + KK*DDIM)  // 67584

typedef __attribute__((ext_vector_type(8))) short bf16x8;
typedef __attribute__((ext_vector_type(4))) float f32x4;

// float -> bf16 RNE (inputs finite; no NaN handling needed)
__device__ __forceinline__ short f2bf(float f) {
  unsigned u = __builtin_bit_cast(unsigned, f);
  u += 0x7fffu + ((u >> 16) & 1u);
  return (short)(u >> 16);
}
__device__ __forceinline__ unsigned pack2(float lo, float hi) {
  return (unsigned)(unsigned short)f2bf(lo) | ((unsigned)(unsigned short)f2bf(hi) << 16);
}

// ---------------------------------------------------------------------------
// K0: W fp32 -> bf16 once. 65536 elems, 32 blocks x 256 x 8.
// ---------------------------------------------------------------------------
__global__ __launch_bounds__(256) void k_prep(const float* __restrict__ W,
                                              short* __restrict__ Wb) {
  int i = (blockIdx.x * 256 + threadIdx.x) * 8;
  float4 a = *(const float4*)(W + i);
  float4 b = *(const float4*)(W + i + 4);
  bf16x8 o = {f2bf(a.x), f2bf(a.y), f2bf(a.z), f2bf(a.w),
              f2bf(b.x), f2bf(b.y), f2bf(b.z), f2bf(b.w)};
  *(bf16x8*)(Wb + i) = o;
}

// ---------------------------------------------------------------------------
// K1: fused logits GEMM (bf16 MFMA) + ssq + softmax + mask.
// Latency fix: per K-half, issue ALL 16 x-loads + 16 W-loads before compute
// (32 VMEM in flight). Invalid frames (m >= len) are exec-masked zero-fill:
// no HBM traffic, logits row = 0, a masked to 0 later -> still correct.
// Grid 512 x 256; block = 16 frames; 4 waves split D=2048.
// ---------------------------------------------------------------------------
__global__ __launch_bounds__(256, 2) void k_logits(const float* __restrict__ x,
    const int* __restrict__ lengths, const short* __restrict__ Wb,
    short* __restrict__ aT, float* __restrict__ asum_p) {
  const int t = threadIdx.x, wv = t >> 6, lane = t & 63;
  const int l15 = lane & 15, quad = lane >> 4;
  const int fg = blockIdx.x;           // 0..511
  const int g0 = fg * 16;              // first frame of block
  const int b  = fg >> 3;              // 8 blocks per batch
  const int m0 = (fg & 7) * 16;        // frame offset within batch
  const int len = lengths[b];
  const bool av = (m0 + l15) < len;    // lane's frame valid (const over loop)

  const float* xrow = x + (size_t)(g0 + l15) * DDIM + wv * 512 + quad * 8;
  const short* w0   = Wb + l15 * DDIM + wv * 512 + quad * 8;
  const short* w1   = w0 + 16 * DDIM;

  f32x4 c0 = {0.f, 0.f, 0.f, 0.f}, c1 = {0.f, 0.f, 0.f, 0.f};
  float ssq = 0.f;
  #pragma unroll
  for (int h = 0; h < 2; ++h) {
    float4 xa[8], xc[8];
    bf16x8 B0[8], B1[8];
    #pragma unroll
    for (int s = 0; s < 8; ++s) {
      const int so = h * 8 + s;
      if (av) {
        xa[s] = *(const float4*)(xrow + so * 32);
        xc[s] = *(const float4*)(xrow + so * 32 + 4);
      } else {
        xa[s] = make_float4(0.f, 0.f, 0.f, 0.f);
        xc[s] = make_float4(0.f, 0.f, 0.f, 0.f);
      }
      B0[s] = *(const bf16x8*)(w0 + so * 32);
      B1[s] = *(const bf16x8*)(w1 + so * 32);
    }
    #pragma unroll
    for (int s = 0; s < 8; ++s) {
      ssq = fmaf(xa[s].x, xa[s].x, ssq); ssq = fmaf(xa[s].y, xa[s].y, ssq);
      ssq = fmaf(xa[s].z, xa[s].z, ssq); ssq = fmaf(xa[s].w, xa[s].w, ssq);
      ssq = fmaf(xc[s].x, xc[s].x, ssq); ssq = fmaf(xc[s].y, xc[s].y, ssq);
      ssq = fmaf(xc[s].z, xc[s].z, ssq); ssq = fmaf(xc[s].w, xc[s].w, ssq);
      bf16x8 A = {f2bf(xa[s].x), f2bf(xa[s].y), f2bf(xa[s].z), f2bf(xa[s].w),
                  f2bf(xc[s].x), f2bf(xc[s].y), f2bf(xc[s].z), f2bf(xc[s].w)};
      c0 = __builtin_amdgcn_mfma_f32_16x16x32_bf16(A, B0[s], c0, 0, 0, 0);
      c1 = __builtin_amdgcn_mfma_f32_16x16x32_bf16(A, B1[s], c1, 0, 0, 0);
    }
  }

  // ssq partial covers frame g0+l15 at this wave+quad's d-offsets
  ssq += __shfl_xor(ssq, 16, 64);
  ssq += __shfl_xor(ssq, 32, 64);
  __shared__ float sq[4][16];
  __shared__ float lg[4][16][33];
  if (quad == 0) sq[wv][l15] = ssq;
  // C layout: row(frame) = quad*4+reg, col(k) = l15
  #pragma unroll
  for (int r = 0; r < 4; ++r) {
    lg[wv][quad * 4 + r][l15]      = c0[r];
    lg[wv][quad * 4 + r][16 + l15] = c1[r];
  }
  __syncthreads();

  // 16 threads per frame, 2 clusters each
  const int fr = t >> 4, kk = (t & 15) * 2;
  float s0 = 0.f, s1 = 0.f;
  #pragma unroll
  for (int w = 0; w < 4; ++w) { s0 += lg[w][fr][kk]; s1 += lg[w][fr][kk + 1]; }
  float ss  = sq[0][fr] + sq[1][fr] + sq[2][fr] + sq[3][fr];
  float inv = 1.f / fmaxf(sqrtf(ss), 1e-12f);
  s0 *= inv; s1 *= inv;
  float mx = fmaxf(s0, s1);
  mx = fmaxf(mx, __shfl_xor(mx, 1, 64));
  mx = fmaxf(mx, __shfl_xor(mx, 2, 64));
  mx = fmaxf(mx, __shfl_xor(mx, 4, 64));
  mx = fmaxf(mx, __shfl_xor(mx, 8, 64));
  float e0 = __expf(s0 - mx), e1 = __expf(s1 - mx);
  float se = e0 + e1;
  se += __shfl_xor(se, 1, 64);
  se += __shfl_xor(se, 2, 64);
  se += __shfl_xor(se, 4, 64);
  se += __shfl_xor(se, 8, 64);
  const bool valid = (m0 + fr) < len;
  float rr = valid ? (1.f / se) : 0.f;
  float a0 = e0 * rr, a1 = e1 * rr;

  __syncthreads();                    // done reading lg; reuse for asum
  lg[0][fr][kk] = a0; lg[0][fr][kk + 1] = a1;
  __syncthreads();
  if (t < KK) {
    float s = 0.f;
    #pragma unroll
    for (int f = 0; f < 16; ++f) s += lg[0][f][t];
    asum_p[(size_t)fg * KK + t] = s;
  }
  // a' = a * invn, transposed store [b][k][m]
  short* ap = aT + (size_t)b * KK * MM + m0 + fr;
  ap[(size_t)kk * MM]       = f2bf(a0 * inv);
  ap[(size_t)(kk + 1) * MM] = f2bf(a1 * inv);
}

// ---------------------------------------------------------------------------
// K2: vlad GEMM (bf16 MFMA). Latency fix: preload ALL 32 x-float4s (masked
// zero-fill for m>=len -> halves fetch, makes avgpool mask free) + all 8
// A-frags before the LDS/MFMA phase. XOR-swizzled wave-private LDS transpose
// (stores 4-way, reads 2-way=free). Grid (8 dc, 64 b) x 256.
// ---------------------------------------------------------------------------
__global__ __launch_bounds__(256, 2) void k_vlad(const float* __restrict__ x,
    const int* __restrict__ lengths, const float* __restrict__ Cc,
    const short* __restrict__ aT, const float* __restrict__ asum_p,
    float* __restrict__ out, float* __restrict__ ssq_part) {
  const int t = threadIdx.x, wv = t >> 6, lane = t & 63;
  const int l15 = lane & 15, quad = lane >> 4;
  const int dc = blockIdx.x, b = blockIdx.y;
  const int dw0 = dc * 256 + wv * 64;   // wave d-base
  const int len = lengths[b];

  __shared__ short xbt[4][64][40];      // [wave][d-local][swizzled m], 80B rows
  __shared__ float asl[KK];
  __shared__ float ssw[4][33];

  if (t < KK) {
    float s = 0.f;
    #pragma unroll
    for (int p = 0; p < 8; ++p) s += asum_p[(size_t)(b * 8 + p) * KK + t];
    asl[t] = s;
  }

  const float* xb  = x  + (size_t)b * MM * DDIM;
  const short* at0 = aT + (size_t)b * KK * MM + l15 * MM + quad * 8;

  const int q4   = l15 * 4;             // lane's 4 staged d-rows
  const int mrow = quad * 2;            // even m within pass group
  const int keyw = l15 & 3;             // store swizzle key
  const int keyr = (l15 >> 2) & 3;      // read swizzle key

  // ---- preload A-frags (L2-hot, 32B/lane x 4) ----
  bf16x8 A0[4], A1[4];
  #pragma unroll
  for (int ms = 0; ms < 4; ++ms) {
    A0[ms] = *(const bf16x8*)(at0 + ms * 32);
    A1[ms] = *(const bf16x8*)(at0 + 16 * MM + ms * 32);
  }

  // ---- preload all x (32 independent float4 loads in flight, masked) ----
  float4 v0[16], v1[16];
  #pragma unroll
  for (int ms = 0; ms < 4; ++ms) {
    #pragma unroll
    for (int p = 0; p < 4; ++p) {
      const int m = ms * 32 + p * 8 + mrow;
      const float* xr = xb + (size_t)m * DDIM + dw0 + q4;
      v0[ms * 4 + p] = (m < len) ? *(const float4*)xr
                                 : make_float4(0.f, 0.f, 0.f, 0.f);
      v1[ms * 4 + p] = (m + 1 < len) ? *(const float4*)(xr + DDIM)
                                     : make_float4(0.f, 0.f, 0.f, 0.f);
    }
  }

  // avgpool (zero-fill makes masking free)
  float avg[4] = {0.f, 0.f, 0.f, 0.f};
  #pragma unroll
  for (int i = 0; i < 16; ++i) {
    avg[0] += v0[i].x + v1[i].x;
    avg[1] += v0[i].y + v1[i].y;
    avg[2] += v0[i].z + v1[i].z;
    avg[3] += v0[i].w + v1[i].w;
  }

  f32x4 acc[2][4];
  #pragma unroll
  for (int kt = 0; kt < 2; ++kt)
    #pragma unroll
    for (int nt = 0; nt < 4; ++nt) acc[kt][nt] = (f32x4){0.f, 0.f, 0.f, 0.f};

  #pragma unroll
  for (int ms = 0; ms < 4; ++ms) {
    #pragma unroll
    for (int p = 0; p < 4; ++p) {
      const int i = ms * 4 + p;
      const int mls = (p ^ keyw) * 8 + mrow;  // swizzled m-slot
      *(unsigned*)&xbt[wv][q4 + 0][mls] = pack2(v0[i].x, v1[i].x);
      *(unsigned*)&xbt[wv][q4 + 1][mls] = pack2(v0[i].y, v1[i].y);
      *(unsigned*)&xbt[wv][q4 + 2][mls] = pack2(v0[i].z, v1[i].z);
      *(unsigned*)&xbt[wv][q4 + 3][mls] = pack2(v0[i].w, v1[i].w);
    }
    // wave-private tile: same-wave DS ordering is program order
    #pragma unroll
    for (int nt = 0; nt < 4; ++nt) {
      bf16x8 B = *(const bf16x8*)&xbt[wv][nt * 16 + l15][(quad ^ keyr) * 8];
      acc[0][nt] = __builtin_amdgcn_mfma_f32_16x16x32_bf16(A0[ms], B, acc[0][nt], 0, 0, 0);
      acc[1][nt] = __builtin_amdgcn_mfma_f32_16x16x32_bf16(A1[ms], B, acc[1][nt], 0, 0, 0);
    }
  }

  #pragma unroll
  for (int c = 0; c < 4; ++c) {
    avg[c] += __shfl_xor(avg[c], 16, 64);
    avg[c] += __shfl_xor(avg[c], 32, 64);
  }
  if (quad == 0) {
    float rl = 1.f / (float)len;
    *(float4*)(out + (size_t)b * OUTROW + dw0 + q4) =
        make_float4(avg[0] * rl, avg[1] * rl, avg[2] * rl, avg[3] * rl);
  }

  __syncthreads();   // asl ready
  float* orow = out + (size_t)b * OUTROW + DDIM;
  #pragma unroll
  for (int kt = 0; kt < 2; ++kt) {
    #pragma unroll
    for (int r = 0; r < 4; ++r) {
      const int k = kt * 16 + quad * 4 + r;
      const float as = asl[k];
      float sqv = 0.f;
      #pragma unroll
      for (int nt = 0; nt < 4; ++nt) {
        const int d = dw0 + nt * 16 + l15;
        float v = acc[kt][nt][r] - as * Cc[(size_t)k * DDIM + d];
        orow[(size_t)k * DDIM + d] = v;
        sqv = fmaf(v, v, sqv);
      }
      sqv += __shfl_xor(sqv, 1, 64);
      sqv += __shfl_xor(sqv, 2, 64);
      sqv += __shfl_xor(sqv, 4, 64);
      sqv += __shfl_xor(sqv, 8, 64);
      if (l15 == 0) ssw[wv][k] = sqv;
    }
  }
  __syncthreads();
  if (t < KK)
    ssq_part[((size_t)dc * BB + b) * KK + t] =
        ssw[0][t] + ssw[1][t] + ssw[2][t] + ssw[3][t];
}

// ---------------------------------------------------------------------------
// K3: fused scales + apply. grid (32 k, 64 b) x 256.
// ---------------------------------------------------------------------------
__global__ __launch_bounds__(256) void k_norm(const float* __restrict__ ssq_part,
    float* __restrict__ out) {
  const int t = threadIdx.x;
  const int k = blockIdx.x;
  const int b = blockIdx.y;
  __shared__ float ssk[32];
  if (t < 32) {
    float sk = 0.f;
    #pragma unroll
    for (int dc = 0; dc < 8; ++dc)
      sk += ssq_part[((size_t)dc * BB + b) * KK + t];
    ssk[t] = sk;
  }
  __syncthreads();
  float gss = 0.f, iv_own = 0.f;
  #pragma unroll
  for (int kk = 0; kk < 32; ++kk) {
    float nk = sqrtf(ssk[kk]);
    float iv = 1.f / fmaxf(nk, 1e-12f);
    float nn = nk * iv;
    gss += nn * nn;
    if (kk == k) iv_own = iv;
  }
  float sc = iv_own / fmaxf(sqrtf(gss), 1e-12f);
  float* row = out + (size_t)b * OUTROW + DDIM + (size_t)k * DDIM;
  #pragma unroll
  for (int h = 0; h < 2; ++h) {
    float4* p = (float4*)(row + h * 1024 + t * 4);
    float4 v = *p;
    v.x *= sc; v.y *= sc; v.z *= sc; v.w *= sc;
    *p = v;
  }
}

// ---------------------------------------------------------------------------
extern "C" void kernel_launch(void* const* d_in, const int* in_sizes, int n_in,
                              void* d_out, int out_size, void* d_ws, size_t ws_size,
                              hipStream_t stream) {
  const float* x       = (const float*)d_in[0];
  const int*   lengths = (const int*)d_in[1];
  const float* W       = (const float*)d_in[2];
  const float* C       = (const float*)d_in[3];
  float* out = (float*)d_out;

  short* Wb     = (short*)d_ws;                          // 32*2048 shorts
  short* aT     = Wb + (size_t)KK * DDIM;                // 64*32*128 shorts
  float* asum_p = (float*)(aT + (size_t)BB * KK * MM);   // 512*32
  float* ssqp   = asum_p + (size_t)512 * KK;             // 8*64*32

  k_prep  <<<dim3(32),     256, 0, stream>>>(W, Wb);
  k_logits<<<dim3(512),    256, 0, stream>>>(x, lengths, Wb, aT, asum_p);
  k_vlad  <<<dim3(8, BB),  256, 0, stream>>>(x, lengths, C, aT, asum_p, out, ssqp);
  k_norm  <<<dim3(KK, BB), 256, 0, stream>>>(ssqp, out);
}